// Round 18
// baseline (94.147 us; speedup 1.0000x reference)
//
#include <hip/hip_runtime.h>
#include <hip/hip_bf16.h>
#include <math.h>

#define B_   16
#define N_   32
#define I_   1152
#define DIN  16
#define D_   64
#define TI   16            // i's per k_xhat block
#define IB   (I_/TI)       // 72 i-tiles
#define IC   16            // i-chunks in routing (72 i each)
#define BND  (B_*N_*D_)    // 32768

#if __has_builtin(__builtin_amdgcn_exp2f)
#define EXP2(x) __builtin_amdgcn_exp2f(x)
#else
#define EXP2(x) exp2f(x)
#endif

#define LOG2E 1.4426950408889634f

typedef __attribute__((ext_vector_type(8))) short short8v;
typedef __attribute__((ext_vector_type(4))) float f32x4;
typedef __attribute__((ext_vector_type(4))) unsigned int u32x4;
typedef __attribute__((ext_vector_type(2))) unsigned int u32x2;

__device__ __forceinline__ float squash1(float s) {
    float sq = s * s;
    return (sq / (1.0f + sq)) * s * rsqrtf(sq + 1e-9f);
}
__device__ __forceinline__ float bff(unsigned int hi16) {
    return __builtin_bit_cast(float, hi16 << 16);
}
// HW packed fp32->bf16 RNE: dst[15:0]=bf16(a), dst[31:16]=bf16(b). 1 VALU op.
__device__ __forceinline__ unsigned int cvtpk(float a, float b) {
    unsigned int r;
    asm("v_cvt_pk_bf16_f32 %0, %1, %2" : "=v"(r) : "v"(a), "v"(b));
    return r;
}

// K1: x_hat via MFMA (R13, best validated). TI=16, reg-pipelined W stream,
// LDS-staged bf16 inputs, lane-order coalesced xh2 stores.
// hi = fp32 bit-truncation packed by v_perm; lo = RNE residual via v_cvt_pk;
// K 0..15 = W_hi, 16..31 = W_lo, inputs duplicated -> fp32-grade W precision.
// C-frag: col b=l&15, d = mt*16+(l>>4)*4+r. xh2 tile element off = mt*256+4l.
// NOTE (R5-R17 post-mortems): k_xhat is pinned at ~2TB/s effective read by a
// per-CU miss-tracking ceiling (~64 lines) x ~50% L3 residency of W; ~10
// issue-structure variants were all neutral. Do not re-attack.
__global__ __launch_bounds__(256, 3) void k_xhat(const float* __restrict__ inp,
                                                 const float* __restrict__ W,
                                                 unsigned short* __restrict__ xh2,
                                                 float* __restrict__ part) {
    __shared__ __align__(16) unsigned short xs[4096];
    const int bx = blockIdx.x;
    const int n  = bx / IB;
    const int ib = bx % IB;
    const int i0 = ib * TI;
    const int t  = threadIdx.x;
    const int l  = t & 63;
    const int mt = t >> 6;
    const int row = l & 15;
    const int ko  = (l >> 4) & 1;
    const bool loHalf = (l >= 32);

    #pragma unroll
    for (int rep = 0; rep < 2; ++rep) {
        int s   = rep * 256 + t;
        int bb  = s >> 5;
        int il  = (s >> 1) & 15;
        int sko = s & 1;
        const float* src = inp + (size_t)bb * (I_ * DIN) + (size_t)(i0 + il) * DIN + sko * 8;
        f32x4 a0 = *(const f32x4*)src;
        f32x4 a1 = *(const f32x4*)(src + 4);
        u32x4 p;
        p.x = cvtpk(a0.x, a0.y);
        p.y = cvtpk(a0.z, a0.w);
        p.z = cvtpk(a1.x, a1.y);
        p.w = cvtpk(a1.z, a1.w);
        int base = (bb * 512 + il * 32 + sko * 16) ^ ((bb & 7) << 4);
        *(u32x4*)((char*)xs + base) = p;
    }
    __syncthreads();

    const float* wb = W + ((size_t)(n * I_ + i0) * 64 + mt * 16 + row) * 16 + ko * 8;

    unsigned int pk[TI * 2];
    f32x4 s0v = {0.f, 0.f, 0.f, 0.f};

#define LOADG(DST, C) {                                                        \
        _Pragma("unroll")                                                      \
        for (int j = 0; j < 4; ++j) {                                          \
            const f32x4* p = (const f32x4*)(wb + (size_t)((C) * 4 + j) * 1024);\
            DST[2 * j] = p[0]; DST[2 * j + 1] = p[1];                          \
        } }

#define COMPG(SRC, C) {                                                        \
        _Pragma("unroll")                                                      \
        for (int j = 0; j < 4; ++j) {                                          \
            const int i = (C) * 4 + j;                                         \
            f32x4 w0 = SRC[2 * j], w1 = SRC[2 * j + 1];                        \
            u32x4 b0 = __builtin_bit_cast(u32x4, w0);                          \
            u32x4 b1 = __builtin_bit_cast(u32x4, w1);                          \
            u32x4 ah, al;                                                      \
            ah.x = __builtin_amdgcn_perm(b0.y, b0.x, 0x07060302u);             \
            ah.y = __builtin_amdgcn_perm(b0.w, b0.z, 0x07060302u);             \
            ah.z = __builtin_amdgcn_perm(b1.y, b1.x, 0x07060302u);             \
            ah.w = __builtin_amdgcn_perm(b1.w, b1.z, 0x07060302u);             \
            float r0 = w0.x - __builtin_bit_cast(float, b0.x & 0xffff0000u);   \
            float r1 = w0.y - __builtin_bit_cast(float, b0.y & 0xffff0000u);   \
            float r2 = w0.z - __builtin_bit_cast(float, b0.z & 0xffff0000u);   \
            float r3 = w0.w - __builtin_bit_cast(float, b0.w & 0xffff0000u);   \
            float r4 = w1.x - __builtin_bit_cast(float, b1.x & 0xffff0000u);   \
            float r5 = w1.y - __builtin_bit_cast(float, b1.y & 0xffff0000u);   \
            float r6 = w1.z - __builtin_bit_cast(float, b1.z & 0xffff0000u);   \
            float r7 = w1.w - __builtin_bit_cast(float, b1.w & 0xffff0000u);   \
            al.x = cvtpk(r0, r1);                                              \
            al.y = cvtpk(r2, r3);                                              \
            al.z = cvtpk(r4, r5);                                              \
            al.w = cvtpk(r6, r7);                                              \
            u32x4 aw;                                                          \
            aw.x = loHalf ? al.x : ah.x;                                       \
            aw.y = loHalf ? al.y : ah.y;                                       \
            aw.z = loHalf ? al.z : ah.z;                                       \
            aw.w = loHalf ? al.w : ah.w;                                       \
            short8v afrag = __builtin_bit_cast(short8v, aw);                   \
            int xaddr = ((l & 15) * 512 + i * 32 + ko * 16) ^ (((l & 15) & 7) << 4); \
            short8v bfrag = *(const short8v*)((const char*)xs + xaddr);        \
            f32x4 acc = __builtin_amdgcn_mfma_f32_16x16x32_bf16(               \
                afrag, bfrag, (f32x4){0.f, 0.f, 0.f, 0.f}, 0, 0, 0);           \
            s0v += acc;                                                        \
            pk[i * 2]     = cvtpk(acc[0], acc[1]);                             \
            pk[i * 2 + 1] = cvtpk(acc[2], acc[3]);                             \
        } }

    f32x4 wA[8], wB[8];
    LOADG(wA, 0)
    LOADG(wB, 1)
    COMPG(wA, 0)
    LOADG(wA, 2)
    COMPG(wB, 1)
    LOADG(wB, 3)
    COMPG(wA, 2)
    COMPG(wB, 3)
#undef LOADG
#undef COMPG

    size_t pidx = (((size_t)ib * B_ + (l & 15)) * N_ + n) * 64 + mt * 16 + (l >> 4) * 4;
    *(f32x4*)(part + pidx) = s0v;

    #pragma unroll
    for (int i = 0; i < TI; ++i) {
        u32x2 v;
        v.x = pk[i * 2];
        v.y = pk[i * 2 + 1];
        size_t off = (size_t)(n * I_ + i0 + i) * 1024 + (size_t)t * 4;
        *reinterpret_cast<u32x2*>(xh2 + off) = v;
    }
}

// K2 (fused: old k_out0 + k_rpart#1): per-block prologue reduces part over
// ib (redundant per-n 16x, all L2/L3 hits) -> coef0 = squash(mean); jc==0
// blocks persist coef0 for K3. Then the 72-i z,a pass over xh2.
// Thread t: b=t&15, d0=(t>>4)*4; xh2 tile is lane-ordered (offset 4t).
__global__ __launch_bounds__(256) void k_rp1(const unsigned short* __restrict__ xh2,
                                             const float* __restrict__ part,
                                             float* __restrict__ coef0buf,
                                             float* __restrict__ part2a) {
    const int bx = blockIdx.x;
    const int n  = bx >> 4;
    const int jc = bx & 15;
    const int t  = threadIdx.x;
    const int b  = t & 15;
    const int d0 = (t >> 4) * 4;

    // prologue: coef0 = squash(mean over i) from part[ib][b][n][d]
    f32x4 s = {0.f, 0.f, 0.f, 0.f};
    const float* pb = part + ((size_t)b * N_ + n) * 64 + d0;
    #pragma unroll 8
    for (int ib = 0; ib < IB; ++ib)
        s += *(const f32x4*)(pb + (size_t)ib * BND);
    float c2[4], c0[4];
    #pragma unroll
    for (int r = 0; r < 4; ++r) {
        c0[r] = squash1(s[r] * (1.0f / (float)I_));
        c2[r] = c0[r] * LOG2E;
    }
    if (jc == 0)
        *(f32x4*)(coef0buf + ((size_t)b * N_ + n) * 64 + d0) = (f32x4){c0[0], c0[1], c0[2], c0[3]};

    const unsigned short* base = xh2 + ((size_t)n * I_ + (size_t)jc * (I_ / IC)) * 1024
                               + (size_t)t * 4;
    float z[4] = {0, 0, 0, 0}, a[4] = {0, 0, 0, 0};
    #pragma unroll 8
    for (int i = 0; i < I_ / IC; ++i) {
        u32x2 u = *(const u32x2*)(base + (size_t)i * 1024);
        unsigned short s4[4] = {(unsigned short)(u.x & 0xffffu), (unsigned short)(u.x >> 16),
                                (unsigned short)(u.y & 0xffffu), (unsigned short)(u.y >> 16)};
        #pragma unroll
        for (int j = 0; j < 4; ++j) {
            float x = bff(s4[j]);
            float e = EXP2(x * c2[j]);
            z[j] += e;
            a[j] = fmaf(e, x, a[j]);
        }
    }

    size_t pidx = ((((size_t)jc * N_ + n) * 16 + b) * 64 + d0) * 2;
    *(f32x4*)(part2a + pidx)     = (f32x4){z[0], a[0], z[1], a[1]};
    *(f32x4*)(part2a + pidx + 4) = (f32x4){z[2], a[2], z[3], a[3]};
}

// K3 (fused: old k_rfin(0) + k_rpart#2): prologue loads coef0, reduces
// part2a over ic -> coef1 = coef0 + squash(A/Z). Then the second z,a pass.
__global__ __launch_bounds__(256) void k_rp2(const unsigned short* __restrict__ xh2,
                                             const float* __restrict__ coef0buf,
                                             const float* __restrict__ part2a,
                                             float* __restrict__ part2b) {
    const int bx = blockIdx.x;
    const int n  = bx >> 4;
    const int jc = bx & 15;
    const int t  = threadIdx.x;
    const int b  = t & 15;
    const int d0 = (t >> 4) * 4;

    // prologue: coef1 = coef0 + squash(A/Z) from part2a[ic][n][b][d][2]
    f32x4 Z = {0.f, 0.f, 0.f, 0.f}, A = {0.f, 0.f, 0.f, 0.f};
    const float* pa = part2a + (((size_t)n * 16 + b) * 64 + d0) * 2;
    #pragma unroll
    for (int ic = 0; ic < IC; ++ic) {
        f32x4 v0 = *(const f32x4*)(pa + (size_t)ic * (BND * 2));
        f32x4 v1 = *(const f32x4*)(pa + (size_t)ic * (BND * 2) + 4);
        Z += (f32x4){v0[0], v0[2], v1[0], v1[2]};
        A += (f32x4){v0[1], v0[3], v1[1], v1[3]};
    }
    f32x4 c0 = *(const f32x4*)(coef0buf + ((size_t)b * N_ + n) * 64 + d0);
    float c2[4];
    #pragma unroll
    for (int r = 0; r < 4; ++r)
        c2[r] = (c0[r] + squash1(A[r] / Z[r])) * LOG2E;

    const unsigned short* base = xh2 + ((size_t)n * I_ + (size_t)jc * (I_ / IC)) * 1024
                               + (size_t)t * 4;
    float z[4] = {0, 0, 0, 0}, a[4] = {0, 0, 0, 0};
    #pragma unroll 8
    for (int i = 0; i < I_ / IC; ++i) {
        u32x2 u = *(const u32x2*)(base + (size_t)i * 1024);
        unsigned short s4[4] = {(unsigned short)(u.x & 0xffffu), (unsigned short)(u.x >> 16),
                                (unsigned short)(u.y & 0xffffu), (unsigned short)(u.y >> 16)};
        #pragma unroll
        for (int j = 0; j < 4; ++j) {
            float x = bff(s4[j]);
            float e = EXP2(x * c2[j]);
            z[j] += e;
            a[j] = fmaf(e, x, a[j]);
        }
    }

    size_t pidx = ((((size_t)jc * N_ + n) * 16 + b) * 64 + d0) * 2;
    *(f32x4*)(part2b + pidx)     = (f32x4){z[0], a[0], z[1], a[1]};
    *(f32x4*)(part2b + pidx + 4) = (f32x4){z[2], a[2], z[3], a[3]};
}

// K4: final reduce + squash -> out[b][n][d]
__global__ __launch_bounds__(256) void k_rfin(const float* __restrict__ part2b,
                                              float* __restrict__ outp) {
    const int gid = blockIdx.x * 256 + threadIdx.x;     // n*1024 + b*64 + d
    float Z = 0.0f, A = 0.0f;
    #pragma unroll
    for (int ic = 0; ic < IC; ++ic) {
        const float* p = part2b + ((size_t)ic * BND + gid) * 2;
        Z += p[0];
        A += p[1];
    }
    const int d = gid & 63, b = (gid >> 6) & 15, n = gid >> 10;
    outp[(b * N_ + n) * D_ + d] = squash1(A / Z);
}

extern "C" void kernel_launch(void* const* d_in, const int* in_sizes, int n_in,
                              void* d_out, int out_size, void* d_ws, size_t ws_size,
                              hipStream_t stream) {
    const float* inp = (const float*)d_in[0];
    const float* W   = (const float*)d_in[1];
    float* out = (float*)d_out;

    unsigned short* xh2 = (unsigned short*)d_ws;                    // 75,497,472 B
    float* part   = (float*)((char*)d_ws + 75497472);               //  9,437,184 B
    float* part2a = (float*)((char*)d_ws + 84934656);               //  4,194,304 B
    float* part2b = (float*)((char*)d_ws + 89128960);               //  4,194,304 B
    float* coef0  = (float*)((char*)d_ws + 93323264);               //    131,072 B

    k_xhat<<<dim3(N_ * IB), dim3(256), 0, stream>>>(inp, W, xh2, part);
    k_rp1 <<<dim3(N_ * IC), dim3(256), 0, stream>>>(xh2, part, coef0, part2a);
    k_rp2 <<<dim3(N_ * IC), dim3(256), 0, stream>>>(xh2, coef0, part2a, part2b);
    k_rfin<<<dim3(BND / 256), dim3(256), 0, stream>>>(part2b, out);
}

// Round 19
// 75.626 us; speedup vs baseline: 1.2449x; 1.2449x over previous
//
#include <hip/hip_runtime.h>
#include <hip/hip_bf16.h>
#include <math.h>

#define B_   16
#define N_   32
#define I_   1152
#define DIN  16
#define D_   64
#define TI   16            // i's per k_xhat block
#define IB   (I_/TI)       // 72 i-tiles
#define IC   16            // i-chunks in routing (72 i each)
#define BND  (B_*N_*D_)    // 32768

#if __has_builtin(__builtin_amdgcn_exp2f)
#define EXP2(x) __builtin_amdgcn_exp2f(x)
#else
#define EXP2(x) exp2f(x)
#endif

#define LOG2E 1.4426950408889634f

typedef __attribute__((ext_vector_type(8))) short short8v;
typedef __attribute__((ext_vector_type(4))) float f32x4;
typedef __attribute__((ext_vector_type(4))) unsigned int u32x4;
typedef __attribute__((ext_vector_type(2))) unsigned int u32x2;

__device__ __forceinline__ float squash1(float s) {
    float sq = s * s;
    return (sq / (1.0f + sq)) * s * rsqrtf(sq + 1e-9f);
}
__device__ __forceinline__ float bff(unsigned int hi16) {
    return __builtin_bit_cast(float, hi16 << 16);
}
// HW packed fp32->bf16 RNE: dst[15:0]=bf16(a), dst[31:16]=bf16(b). 1 VALU op.
__device__ __forceinline__ unsigned int cvtpk(float a, float b) {
    unsigned int r;
    asm("v_cvt_pk_bf16_f32 %0, %1, %2" : "=v"(r) : "v"(a), "v"(b));
    return r;
}

// ============================ R13 structure (best: 75.8us) ==================
// Session conclusions baked into this file:
//  - k_xhat is pinned at ~2.6TB/s HBM fetch by read-miss latency/concurrency
//    limits: ~10 issue-structure variants (reg prefetch, gload_lds shallow &
//    deep, store placement, conversion cost, occupancy 35-66%) all neutral.
//  - xh2 (bf16, 75MB) is L3-resident for the routing passes -> they're cheap.
//  - Coop/grid-sync path is incompatible with the harness's graph capture
//    (R16: fallback executed in the timed graph) and (256,2)-style bounds cap
//    VGPR at 128 -> pk[144] spills (R10/R16: 380-560us). Do not revisit.
//  - Fusing the tiny reductions into the routing passes ADDS cross-XCD
//    traffic (R18: +18us). Keep the 6-kernel chain.
__global__ __launch_bounds__(256, 3) void k_xhat(const float* __restrict__ inp,
                                                 const float* __restrict__ W,
                                                 unsigned short* __restrict__ xh2,
                                                 float* __restrict__ part) {
    __shared__ __align__(16) unsigned short xs[4096];
    const int bx = blockIdx.x;
    const int n  = bx / IB;
    const int ib = bx % IB;
    const int i0 = ib * TI;
    const int t  = threadIdx.x;
    const int l  = t & 63;
    const int mt = t >> 6;
    const int row = l & 15;
    const int ko  = (l >> 4) & 1;
    const bool loHalf = (l >= 32);

    #pragma unroll
    for (int rep = 0; rep < 2; ++rep) {
        int s   = rep * 256 + t;
        int bb  = s >> 5;
        int il  = (s >> 1) & 15;
        int sko = s & 1;
        const float* src = inp + (size_t)bb * (I_ * DIN) + (size_t)(i0 + il) * DIN + sko * 8;
        f32x4 a0 = *(const f32x4*)src;
        f32x4 a1 = *(const f32x4*)(src + 4);
        u32x4 p;
        p.x = cvtpk(a0.x, a0.y);
        p.y = cvtpk(a0.z, a0.w);
        p.z = cvtpk(a1.x, a1.y);
        p.w = cvtpk(a1.z, a1.w);
        int base = (bb * 512 + il * 32 + sko * 16) ^ ((bb & 7) << 4);
        *(u32x4*)((char*)xs + base) = p;
    }
    __syncthreads();

    const float* wb = W + ((size_t)(n * I_ + i0) * 64 + mt * 16 + row) * 16 + ko * 8;

    unsigned int pk[TI * 2];
    f32x4 s0v = {0.f, 0.f, 0.f, 0.f};

#define LOADG(DST, C) {                                                        \
        _Pragma("unroll")                                                      \
        for (int j = 0; j < 4; ++j) {                                          \
            const f32x4* p = (const f32x4*)(wb + (size_t)((C) * 4 + j) * 1024);\
            DST[2 * j] = p[0]; DST[2 * j + 1] = p[1];                          \
        } }

#define COMPG(SRC, C) {                                                        \
        _Pragma("unroll")                                                      \
        for (int j = 0; j < 4; ++j) {                                          \
            const int i = (C) * 4 + j;                                         \
            f32x4 w0 = SRC[2 * j], w1 = SRC[2 * j + 1];                        \
            u32x4 b0 = __builtin_bit_cast(u32x4, w0);                          \
            u32x4 b1 = __builtin_bit_cast(u32x4, w1);                          \
            u32x4 ah, al;                                                      \
            ah.x = __builtin_amdgcn_perm(b0.y, b0.x, 0x07060302u);             \
            ah.y = __builtin_amdgcn_perm(b0.w, b0.z, 0x07060302u);             \
            ah.z = __builtin_amdgcn_perm(b1.y, b1.x, 0x07060302u);             \
            ah.w = __builtin_amdgcn_perm(b1.w, b1.z, 0x07060302u);             \
            float r0 = w0.x - __builtin_bit_cast(float, b0.x & 0xffff0000u);   \
            float r1 = w0.y - __builtin_bit_cast(float, b0.y & 0xffff0000u);   \
            float r2 = w0.z - __builtin_bit_cast(float, b0.z & 0xffff0000u);   \
            float r3 = w0.w - __builtin_bit_cast(float, b0.w & 0xffff0000u);   \
            float r4 = w1.x - __builtin_bit_cast(float, b1.x & 0xffff0000u);   \
            float r5 = w1.y - __builtin_bit_cast(float, b1.y & 0xffff0000u);   \
            float r6 = w1.z - __builtin_bit_cast(float, b1.z & 0xffff0000u);   \
            float r7 = w1.w - __builtin_bit_cast(float, b1.w & 0xffff0000u);   \
            al.x = cvtpk(r0, r1);                                              \
            al.y = cvtpk(r2, r3);                                              \
            al.z = cvtpk(r4, r5);                                              \
            al.w = cvtpk(r6, r7);                                              \
            u32x4 aw;                                                          \
            aw.x = loHalf ? al.x : ah.x;                                       \
            aw.y = loHalf ? al.y : ah.y;                                       \
            aw.z = loHalf ? al.z : ah.z;                                       \
            aw.w = loHalf ? al.w : ah.w;                                       \
            short8v afrag = __builtin_bit_cast(short8v, aw);                   \
            int xaddr = ((l & 15) * 512 + i * 32 + ko * 16) ^ (((l & 15) & 7) << 4); \
            short8v bfrag = *(const short8v*)((const char*)xs + xaddr);        \
            f32x4 acc = __builtin_amdgcn_mfma_f32_16x16x32_bf16(               \
                afrag, bfrag, (f32x4){0.f, 0.f, 0.f, 0.f}, 0, 0, 0);           \
            s0v += acc;                                                        \
            pk[i * 2]     = cvtpk(acc[0], acc[1]);                             \
            pk[i * 2 + 1] = cvtpk(acc[2], acc[3]);                             \
        } }

    f32x4 wA[8], wB[8];
    LOADG(wA, 0)
    LOADG(wB, 1)
    COMPG(wA, 0)
    LOADG(wA, 2)
    COMPG(wB, 1)
    LOADG(wB, 3)
    COMPG(wA, 2)
    COMPG(wB, 3)
#undef LOADG
#undef COMPG

    size_t pidx = (((size_t)ib * B_ + (l & 15)) * N_ + n) * 64 + mt * 16 + (l >> 4) * 4;
    *(f32x4*)(part + pidx) = s0v;

    #pragma unroll
    for (int i = 0; i < TI; ++i) {
        u32x2 v;
        v.x = pk[i * 2];
        v.y = pk[i * 2 + 1];
        size_t off = (size_t)(n * I_ + i0 + i) * 1024 + (size_t)t * 4;
        *reinterpret_cast<u32x2*>(xh2 + off) = v;
    }
}

// K2: coef = squash(mean over i of x_hat) — routing iteration 0.
__global__ __launch_bounds__(256) void k_out0(const float* __restrict__ part,
                                              float* __restrict__ coef) {
    const int t = blockIdx.x * 256 + threadIdx.x;
    float s = 0.0f;
    for (int j = 0; j < IB; ++j) s += part[(size_t)j * BND + t];
    s *= (1.0f / (float)I_);
    coef[t] = squash1(s);
}

// K3: routing partial pass. xh2 tile is lane-ordered: thread t owns element
// offset 4t per i-tile => wave reads 512B CONTIGUOUS per i.
__global__ __launch_bounds__(256) void k_rpart(const unsigned short* __restrict__ xh2,
                                               const float* __restrict__ coef,
                                               float* __restrict__ part2) {
    const int bx = blockIdx.x;
    const int n  = bx >> 4;
    const int ic = bx & 15;
    const int t  = threadIdx.x;
    const int b  = t & 15;
    const int d0 = (t >> 4) * 4;

    const unsigned short* base = xh2 + ((size_t)n * I_ + (size_t)ic * (I_ / IC)) * 1024
                               + (size_t)t * 4;
    f32x4 c4 = *(const f32x4*)(coef + ((size_t)b * N_ + n) * 64 + d0);
    float c2[4] = {c4.x * LOG2E, c4.y * LOG2E, c4.z * LOG2E, c4.w * LOG2E};
    float z[4] = {0, 0, 0, 0}, a[4] = {0, 0, 0, 0};

    #pragma unroll 8
    for (int i = 0; i < I_ / IC; ++i) {
        u32x2 u = *(const u32x2*)(base + (size_t)i * 1024);
        unsigned short s4[4] = {(unsigned short)(u.x & 0xffffu), (unsigned short)(u.x >> 16),
                                (unsigned short)(u.y & 0xffffu), (unsigned short)(u.y >> 16)};
        #pragma unroll
        for (int j = 0; j < 4; ++j) {
            float x = bff(s4[j]);
            float e = EXP2(x * c2[j]);
            z[j] += e;
            a[j] = fmaf(e, x, a[j]);
        }
    }

    size_t pidx = ((((size_t)ic * N_ + n) * 16 + b) * 64 + d0) * 2;
    f32x4 v0 = {z[0], a[0], z[1], a[1]};
    f32x4 v1 = {z[2], a[2], z[3], a[3]};
    *(f32x4*)(part2 + pidx)     = v0;
    *(f32x4*)(part2 + pidx + 4) = v1;
}

// K4: routing finisher. final=0: coef += squash(a/z). final=1: out = squash.
__global__ __launch_bounds__(256) void k_rfin(const float* __restrict__ part2,
                                              const float* __restrict__ coefIn,
                                              float* __restrict__ outp,
                                              int final_) {
    const int gid = blockIdx.x * 256 + threadIdx.x;
    float Z = 0.0f, A = 0.0f;
    #pragma unroll
    for (int ic = 0; ic < IC; ++ic) {
        const float* p = part2 + ((size_t)ic * BND + gid) * 2;
        Z += p[0];
        A += p[1];
    }
    const int d = gid & 63, b = (gid >> 6) & 15, n = gid >> 10;
    const int ci = (b * N_ + n) * D_ + d;
    float o = squash1(A / Z);
    outp[ci] = final_ ? o : (coefIn[ci] + o);
}

extern "C" void kernel_launch(void* const* d_in, const int* in_sizes, int n_in,
                              void* d_out, int out_size, void* d_ws, size_t ws_size,
                              hipStream_t stream) {
    const float* inp = (const float*)d_in[0];
    const float* W   = (const float*)d_in[1];
    float* out = (float*)d_out;

    unsigned short* xh2 = (unsigned short*)d_ws;                    // 75,497,472 B
    float* part  = (float*)((char*)d_ws + 75497472);                //  9,437,184 B
    float* part2 = (float*)((char*)d_ws + 84934656);                //  4,194,304 B
    float* coef  = (float*)((char*)d_ws + 89128960);                //    131,072 B

    k_xhat<<<dim3(N_ * IB), dim3(256), 0, stream>>>(inp, W, xh2, part);
    k_out0<<<dim3(BND / 256), dim3(256), 0, stream>>>(part, coef);
    k_rpart<<<dim3(N_ * IC), dim3(256), 0, stream>>>(xh2, coef, part2);
    k_rfin <<<dim3(BND / 256), dim3(256), 0, stream>>>(part2, coef, coef, 0);
    k_rpart<<<dim3(N_ * IC), dim3(256), 0, stream>>>(xh2, coef, part2);
    k_rfin <<<dim3(BND / 256), dim3(256), 0, stream>>>(part2, coef, out, 1);
}